// Round 6
// baseline (1762.386 us; speedup 1.0000x reference)
//
#include <hip/hip_runtime.h>

#define E 64
#define D 50
#define SS 384
#define G4 256   // 4*E

__device__ __forceinline__ float fast_rcp(float x){ return __builtin_amdgcn_rcpf(x); }
__device__ __forceinline__ float tanh_fast(float x){
  // tanh(x) = 1 - 2/(exp(2x)+1)
  float e = __expf(2.0f*x);
  return 1.0f - 2.0f*fast_rcp(e + 1.0f);
}
__device__ __forceinline__ float sigmoid_fast(float x){
  return fast_rcp(1.0f + __expf(-x));
}
// whole-wave rotate via DPP (VALU pipe, NOT the DS pipe).
// wave_ror:1: lane i receives the value of lane (i-1)&63.
__device__ __forceinline__ float ror1(float x){
  return __int_as_float(__builtin_amdgcn_update_dpp(
      0, __float_as_int(x), 0x13C /*wave_ror:1*/, 0xF, 0xF, false));
}
__device__ __forceinline__ float rdlane(float v, int l){
  return __int_as_float(__builtin_amdgcn_readlane(__float_as_int(v), l));
}

// ---------------------------------------------------------------------------
// K0: gx[b,s,j] = bias[j] + sum_k emb[sent[b,s],k] * Wih[j,k]   (both LSTMs)
// ---------------------------------------------------------------------------
__global__ __launch_bounds__(256, 1) void gx_kernel(
  const int* __restrict__ sent1, const int* __restrict__ sent2,
  const float* __restrict__ emb,
  const float* __restrict__ Wih1, const float* __restrict__ bih1, const float* __restrict__ bhh1,
  const float* __restrict__ Wih2, const float* __restrict__ bih2, const float* __restrict__ bhh2,
  float* __restrict__ gx1, float* __restrict__ gx2)
{
  const int bb    = blockIdx.x;     // 0..511
  const int which = bb >> 8;
  const int chunk = bb & 255;
  const int j     = threadIdx.x;
  const int*   sent = which ? sent2 : sent1;
  const float* Wih  = which ? Wih2  : Wih1;
  const float* bA   = which ? bih2  : bih1;
  const float* bB   = which ? bhh2  : bhh1;
  float*       gx   = which ? gx2   : gx1;

  float wih[D];
  #pragma unroll
  for (int k=0;k<D;k+=2){
    float2 v = *(const float2*)&Wih[j*D+k];
    wih[k]=v.x; wih[k+1]=v.y;
  }
  const float bias = bA[j] + bB[j];

  __shared__ __align__(16) float xb[8][52];
  const int row0 = chunk*96;
  for (int c=0;c<12;++c){
    const int r0 = row0 + c*8;
    #pragma unroll
    for (int q=0;q<2;++q){
      int tt = j + q*256;
      if (tt < 400){
        int r = tt/50;
        int k = tt - r*50;
        int idx = sent[r0 + r];
        xb[r][k] = emb[(size_t)idx*D + k];
      }
    }
    __syncthreads();
    for (int r=0;r<8;++r){
      float a0=bias, a1=0.f;
      #pragma unroll
      for (int k=0;k<48;k+=4){
        float4 xv = *(const float4*)&xb[r][k];
        a0 += xv.x*wih[k]   + xv.y*wih[k+1];
        a1 += xv.z*wih[k+2] + xv.w*wih[k+3];
      }
      a0 += xb[r][48]*wih[48];
      a1 += xb[r][49]*wih[49];
      gx[(size_t)(r0+r)*G4 + j] = a0+a1;
    }
    __syncthreads();
  }
}

// ---------------------------------------------------------------------------
// K1: both LSTM recurrences. 64 blocks x 256 threads (4 waves).
// DPP rotate-MAC (verified r4).
// ---------------------------------------------------------------------------
__global__ __launch_bounds__(256, 1) void lstm_kernel(
  const float* __restrict__ gx1, const float* __restrict__ gx2,
  const float* __restrict__ Whh1, const float* __restrict__ Whh2,
  const int* __restrict__ s1_len, const int* __restrict__ s2_len,
  float* __restrict__ h1_all, float* __restrict__ out_all,
  float* __restrict__ hn_cap)
{
  const int b = blockIdx.x;
  const int j = threadIdx.x;
  const int lane = j & 63;
  const int wv = j >> 6;
  __shared__ float h_lds[64];
  __shared__ float gates[256];

  float whht[64];                       // whht[i] = Whh[j][(lane-i)&63] (ror direction)
  #pragma unroll
  for (int i=0;i<32;++i){
    whht[i]    = Whh1[j*64 + ((lane-i)&63)];
    whht[i+32] = Whh1[j*64 + ((lane-i+32)&63)];
  }

  const int is_g = (wv==2);             // wave-uniform: gate 'g' uses tanh
  float c_reg=0.f, gh=0.f, gc=0.f, hn=0.f;
  int idx1=0, idx2=0;
  if (j<64){ idx1=s1_len[b*64+j]; idx2=s2_len[b*64+j]; h_lds[j]=0.f; }
  __syncthreads();

  // ---- LSTM1 ----
  {
    const float* gx = gx1 + (size_t)b*SS*G4;
    float* hout = h1_all + (size_t)b*SS*E;
    float gx_cur = gx[j];
    float gx_n1  = gx[G4 + j];
    for (int s=0;s<SS;++s){
      int sn2 = (s+2<SS)? s+2 : SS-1;
      float gx_n2 = gx[(size_t)sn2*G4 + j];
      float hr  = h_lds[lane];          // iter i holds h[(lane-i)&63]
      float hr2 = h_lds[lane^32];       // iter i holds h[(lane-i+32)&63]
      float g0 = gx_cur, g1 = 0.f;
      #pragma unroll
      for (int i=0;i<32;++i){
        g0 = __builtin_fmaf(hr,  whht[i],    g0);
        g1 = __builtin_fmaf(hr2, whht[i+32], g1);
        hr = ror1(hr); hr2 = ror1(hr2);
      }
      float g = g0 + g1;
      gates[j] = is_g ? tanh_fast(g) : sigmoid_fast(g);
      __syncthreads();
      if (j<64){
        float gi=gates[j], gf=gates[64+j], gg=gates[128+j], go=gates[192+j];
        c_reg = gf*c_reg + gi*gg;
        float h = go * tanh_fast(c_reg);
        h_lds[j] = h;
        hout[(size_t)s*E + j] = h;
        if (s==idx1){ gh=h; gc=c_reg; }
      }
      gx_cur = gx_n1; gx_n1 = gx_n2;
      __syncthreads();
    }
  }
  // ---- LSTM2 ----
  #pragma unroll
  for (int i=0;i<32;++i){
    whht[i]    = Whh2[j*64 + ((lane-i)&63)];
    whht[i+32] = Whh2[j*64 + ((lane-i+32)&63)];
  }
  if (j<64){ h_lds[j]=gh; c_reg=gc; }
  __syncthreads();
  {
    const float* gx = gx2 + (size_t)b*SS*G4;
    float* hout = out_all + (size_t)b*SS*E;
    float gx_cur = gx[j];
    float gx_n1  = gx[G4 + j];
    for (int s=0;s<SS;++s){
      int sn2 = (s+2<SS)? s+2 : SS-1;
      float gx_n2 = gx[(size_t)sn2*G4 + j];
      float hr  = h_lds[lane];
      float hr2 = h_lds[lane^32];
      float g0 = gx_cur, g1 = 0.f;
      #pragma unroll
      for (int i=0;i<32;++i){
        g0 = __builtin_fmaf(hr,  whht[i],    g0);
        g1 = __builtin_fmaf(hr2, whht[i+32], g1);
        hr = ror1(hr); hr2 = ror1(hr2);
      }
      float g = g0 + g1;
      gates[j] = is_g ? tanh_fast(g) : sigmoid_fast(g);
      __syncthreads();
      if (j<64){
        float gi=gates[j], gf=gates[64+j], gg=gates[128+j], go=gates[192+j];
        c_reg = gf*c_reg + gi*gg;
        float h = go * tanh_fast(c_reg);
        h_lds[j] = h;
        hout[(size_t)s*E + j] = h;
        if (s==idx2) hn = h;
      }
      gx_cur = gx_n1; gx_n1 = gx_n2;
      __syncthreads();
    }
  }
  if (j<64) hn_cap[b*64+j] = hn;
}

// ---------------------------------------------------------------------------
// K2: E_g[row,f] = exp( 2*(h1[row]@wy + out[row]@wh)[f] )
// ---------------------------------------------------------------------------
__global__ __launch_bounds__(256, 1) void base_kernel(
  const float* __restrict__ h1_all, const float* __restrict__ out_all,
  const float* __restrict__ wy, const float* __restrict__ wh,
  float* __restrict__ E_g)
{
  const int t = threadIdx.x;
  const int wave = t>>6, lane = t&63;
  float wyc[E], whc[E];
  #pragma unroll
  for (int e=0;e<E;++e){ wyc[e]=wy[e*E+lane]; whc[e]=wh[e*E+lane]; }
  const int row0 = blockIdx.x*16 + wave*4;
  for (int r=0;r<4;++r){
    int row = row0 + r;
    float hv = h1_all[(size_t)row*E + lane];
    float ov = out_all[(size_t)row*E + lane];
    float a0=0,a1=0;
    #pragma unroll
    for (int e=0;e<E;++e){
      a0 += rdlane(hv,e)*wyc[e];
      a1 += rdlane(ov,e)*whc[e];
    }
    E_g[(size_t)row*E + lane] = __expf(2.0f*(a0+a1));
  }
}

// ---------------------------------------------------------------------------
// K3: attention scan. 64 blocks x 768 threads (12 waves), 384 steps.
// PAIR-WAVE split of the verified r4 structure:
//   wave pair p owns rows p*64..p*64+63 (row = p*64+lane, duplicated in both
//   halves); half = wv&1 splits the e-range: score loop is 32 elems with
//   wave-uniform readlane indices (half*32+k). Each wave runs ONE of r4's
//   two rotate-MAC chains (w0: off=0 with exr=ex; w1: off=32 with
//   exr=shfl_xor(ex,32)) — indexing byte-identical to the r4-verified code;
//   pair-sum over both waves covers all 64 rows per lane.
// Per-thread state ~105 VGPRs -> no AGPR spills (r5's 150+ spilled at 96).
// 12 waves / 4 SIMDs = 3 waves/SIMD exactly (r4's 6 waves = (2,2,1,1)).
// ---------------------------------------------------------------------------
__global__ __launch_bounds__(768, 1) void attn_kernel(
  const float* __restrict__ h1_all, const float* __restrict__ E_all,
  const float* __restrict__ w, const float* __restrict__ wr, const float* __restrict__ wt,
  const float* __restrict__ s1_s, const int* __restrict__ s2_len,
  float* __restrict__ rn_cap)
{
  const int b = blockIdx.x;
  const int t = threadIdx.x;
  const int wv = t>>6, lane = t&63;
  const int pair = wv>>1;          // 0..5: row group
  const int half = wv&1;           // e-range half
  const int off  = half*32;        // e-offset AND rotate-chain offset
  const int row  = pair*64 + lane;

  __shared__ float2 accP[12*64];   // {acc[e]-partial, tot-partial} per wave
  __shared__ float2 rwrtP[12*64];  // {rw-partial, rt-partial} per wave
  __shared__ float  scoreH[2][6*64];

  const float* h1b = h1_all + (size_t)b*SS*E;
  const float* Eb  = E_all  + (size_t)b*SS*E;

  // ---- preload (once) ----
  float Ee[32];                    // E[row][off..off+32)
  #pragma unroll
  for (int k=0;k<32;k+=4){
    float4 v = *(const float4*)&Eb[(size_t)row*E + off + k];
    Ee[k]=v.x; Ee[k+1]=v.y; Ee[k+2]=v.z; Ee[k+3]=v.w;
  }
  float ht[32];                    // my half of the r4 rotate chain
  #pragma unroll
  for (int i=0;i<32;++i)
    ht[i] = h1b[(size_t)(pair*64 + ((lane-i+off)&63))*E + lane];
  float WSUM = 0.f;
  for (int e=0;e<64;++e) WSUM += w[e];     // uniform -> scalar
  const float s1v = s1_s[b*SS + row];
  const int  idx2 = s2_len[b*E + lane];
  // GEMV k-chunk for this wave (rnew@wr, rnew@wt): 4x6 + 8x5 = 64
  const int k0  = (wv<4)? wv*6 : 24+(wv-4)*5;
  const int cnt = (wv<4)? 6 : 5;
  float wrch[6], wtch[6];
  #pragma unroll
  for (int jj=0;jj<6;++jj){
    int kk = k0 + ((jj<cnt)? jj : 0);
    wrch[jj] = wr[kk*E + lane];
    wtch[jj] = wt[kk*E + lane];
  }

  rwrtP[wv*64+lane] = make_float2(0.f, 0.f);   // r0 = 0 -> rw=0, rt=0
  __syncthreads();

  float rn_keep = 0.f;
  for (int s=0;s<SS;++s){
    // ---- A-pre: reduce rw/rt partials (e = lane), R = exp(2*rw) ----
    float rwl=0.f, rtl=0.f;
    #pragma unroll
    for (int q=0;q<12;++q){ float2 v = rwrtP[q*64+lane]; rwl+=v.x; rtl+=v.y; }
    float Rl = __expf(2.0f*rwl);

    // ---- half-score (32 elems; readlane idx off+k is wave-uniform) ----
    float sc0=0.f, sc1=0.f, sc2=0.f, sc3=0.f;
    #pragma unroll
    for (int k=0;k<32;k+=4){
      float r0=rdlane(Rl,off+k),   r1=rdlane(Rl,off+k+1);
      float r2=rdlane(Rl,off+k+2), r3=rdlane(Rl,off+k+3);
      sc0 = __builtin_fmaf(w[off+k],   fast_rcp(__builtin_fmaf(Ee[k],  r0,1.f)), sc0);
      sc1 = __builtin_fmaf(w[off+k+1], fast_rcp(__builtin_fmaf(Ee[k+1],r1,1.f)), sc1);
      sc2 = __builtin_fmaf(w[off+k+2], fast_rcp(__builtin_fmaf(Ee[k+2],r2,1.f)), sc2);
      sc3 = __builtin_fmaf(w[off+k+3], fast_rcp(__builtin_fmaf(Ee[k+3],r3,1.f)), sc3);
    }
    float myh = (sc0+sc1)+(sc2+sc3);
    scoreH[half][pair*64+lane] = myh;
    __syncthreads();

    // ---- combine halves, softmax numerator ----
    float oth = scoreH[1-half][pair*64+lane];
    float sc = WSUM - 2.0f*(myh + oth);
    float masked = s1v*sc - (1.f - s1v)*1e12f;
    float ex = __expf(masked);       // |sc| <= sum|w| ~ 51 -> fp32 safe

    // ---- one rotate-MAC chain (r4 chain A for half=0, chain B for half=1) ----
    float exr = half ? __shfl_xor(ex, 32) : ex;
    float acc=0.f, tot=0.f;
    #pragma unroll
    for (int i=0;i<32;++i){
      acc = __builtin_fmaf(exr, ht[i], acc);
      tot += exr;
      exr = ror1(exr);
    }
    accP[wv*64+lane] = make_float2(acc, tot);
    __syncthreads();

    // ---- phase C: reduce acc/tot, rnew, distributed GEMV ----
    float av=0.f, tv=0.f;
    #pragma unroll
    for (int q=0;q<12;++q){ float2 v = accP[q*64+lane]; av+=v.x; tv+=v.y; }
    float rnew = __builtin_fmaf(av, fast_rcp(tv), tanh_fast(rtl));
    if (wv==0 && s==idx2) rn_keep = rnew;
    float rwp=0.f, rtp=0.f;
    #pragma unroll
    for (int jj=0;jj<6;++jj){
      if (jj<cnt){
        float rv = rdlane(rnew, k0+jj);
        rwp = __builtin_fmaf(rv, wrch[jj], rwp);
        rtp = __builtin_fmaf(rv, wtch[jj], rtp);
      }
    }
    rwrtP[wv*64+lane] = make_float2(rwp, rtp);
    __syncthreads();
  }
  if (wv==0) rn_cap[b*E + lane] = rn_keep;
}

// ---------------------------------------------------------------------------
// K4: final MLP. 64 blocks x 128 threads.
// ---------------------------------------------------------------------------
__global__ __launch_bounds__(128, 1) void final_kernel(
  const float* __restrict__ rn_cap, const float* __restrict__ hn_cap,
  const float* __restrict__ wp, const float* __restrict__ wx,
  const float* __restrict__ l1W, const float* __restrict__ l1b,
  const float* __restrict__ lW, const float* __restrict__ lb,
  float* __restrict__ out)
{
  const int b = blockIdx.x, t = threadIdx.x;
  __shared__ float rn[E], hn[E], hid1[E], hid2[128];
  if (t<E){ rn[t]=rn_cap[b*E+t]; hn[t]=hn_cap[b*E+t]; }
  __syncthreads();
  if (t<E){
    float a0=0,a1=0;
    #pragma unroll
    for (int k=0;k<E;++k){
      a0 += rn[k]*wp[k*E+t];
      a1 += hn[k]*wx[k*E+t];
    }
    hid1[t] = tanh_fast(a0+a1);
  }
  __syncthreads();
  {
    float acc = l1b[t];
    #pragma unroll
    for (int k=0;k<E;++k) acc += hid1[k]*l1W[t*E+k];
    hid2[t] = tanh_fast(acc);
  }
  __syncthreads();
  if (t<4){
    float acc = lb[t];
    #pragma unroll
    for (int k=0;k<128;++k) acc += hid2[k]*lW[t*128+k];
    out[b*4+t] = acc;
  }
}

extern "C" void kernel_launch(void* const* d_in, const int* in_sizes, int n_in,
                              void* d_out, int out_size, void* d_ws, size_t ws_size,
                              hipStream_t stream)
{
  const int*   sent1 = (const int*)  d_in[0];
  const int*   sent2 = (const int*)  d_in[1];
  const int*   s1len = (const int*)  d_in[2];
  const int*   s2len = (const int*)  d_in[3];
  const float* s1s   = (const float*)d_in[4];
  const float* emb   = (const float*)d_in[6];
  const float* Wih1  = (const float*)d_in[7];
  const float* Whh1  = (const float*)d_in[8];
  const float* bih1  = (const float*)d_in[9];
  const float* bhh1  = (const float*)d_in[10];
  const float* Wih2  = (const float*)d_in[11];
  const float* Whh2  = (const float*)d_in[12];
  const float* bih2  = (const float*)d_in[13];
  const float* bhh2  = (const float*)d_in[14];
  const float* wy    = (const float*)d_in[15];
  const float* wh    = (const float*)d_in[16];
  const float* w     = (const float*)d_in[17];
  const float* wp    = (const float*)d_in[18];
  const float* wx    = (const float*)d_in[19];
  const float* wr    = (const float*)d_in[20];
  const float* wt    = (const float*)d_in[21];
  const float* l1W   = (const float*)d_in[22];
  const float* l1b   = (const float*)d_in[23];
  const float* lW    = (const float*)d_in[24];
  const float* lb    = (const float*)d_in[25];
  float* out = (float*)d_out;

  float* ws  = (float*)d_ws;
  float* gx1 = ws;                         // 64*384*256 = 6291456 floats
  float* gx2 = gx1 + 6291456;
  float* h1  = gx2 + 6291456;              // 64*384*64 = 1572864
  float* outa= h1  + 1572864;
  float* Eg  = outa + 1572864;
  float* rnc = Eg  + 1572864;              // 4096
  float* hnc = rnc + 4096;

  hipLaunchKernelGGL(gx_kernel, dim3(512), dim3(256), 0, stream,
    sent1, sent2, emb, Wih1, bih1, bhh1, Wih2, bih2, bhh2, gx1, gx2);
  hipLaunchKernelGGL(lstm_kernel, dim3(64), dim3(256), 0, stream,
    gx1, gx2, Whh1, Whh2, s1len, s2len, h1, outa, hnc);
  hipLaunchKernelGGL(base_kernel, dim3(1536), dim3(256), 0, stream,
    h1, outa, wy, wh, Eg);
  hipLaunchKernelGGL(attn_kernel, dim3(64), dim3(768), 0, stream,
    h1, Eg, w, wr, wt, s1s, s2len, rnc);
  hipLaunchKernelGGL(final_kernel, dim3(64), dim3(128), 0, stream,
    rnc, hnc, wp, wx, l1W, l1b, lW, lb, out);
}